// Round 3
// baseline (210.963 us; speedup 1.0000x reference)
//
#include <hip/hip_runtime.h>
#include <hip/hip_bf16.h>

// Problem constants (fixed by setup_inputs)
#define NB 4
#define SEQ 2048
#define HID 768
#define NSPAN 16384            // spans per batch
#define M_TOT (NB * NSPAN)     // 65536 rows
#define K2 1536                // 2*HID
#define CMP_CAP 66048          // compacted-table capacity (65536 + pad)

typedef float f32x4 __attribute__((ext_vector_type(4)));
typedef short s16x8 __attribute__((ext_vector_type(8)));
using bf16 = __hip_bfloat16;

// global -> LDS direct (16B per lane). LDS dest is wave-uniform base + lane*16;
// global src is per-lane (gather-capable).
__device__ __forceinline__ void gll16(const void* g, void* l) {
    __builtin_amdgcn_global_load_lds(
        (const __attribute__((address_space(1))) unsigned*)g,
        (__attribute__((address_space(3))) unsigned*)l, 16, 0, 0);
}

// ---------------------------------------------------------------------------
// Detect span_masks dtype: int32 words (0/1) vs byte-packed bools.
// 16384 words = 64 KB is in-bounds under either interpretation.
__global__ void mask_detect_kernel(const unsigned* __restrict__ masks, int* __restrict__ flag) {
    int t = blockIdx.x * 256 + threadIdx.x;
    if (t < 16384) {
        unsigned v = masks[t];
        if (v > 1u) atomicOr(flag, 1);   // multi-byte pattern => byte-packed bools
    }
}

// ---------------------------------------------------------------------------
// Default-fill compacted tables (pad rows: gather M3 row 0, no output store).
__global__ void init_compact_kernel(int* __restrict__ cS, int* __restrict__ cE,
                                    int* __restrict__ cO) {
    int i = blockIdx.x * 256 + threadIdx.x;
    if (i < CMP_CAP) { cS[i] = 0; cE[i] = 0; cO[i] = -1; }
}

// ---------------------------------------------------------------------------
// Compact active rows: append (startRow, endRow, outRow) per masked-in span.
// Append order varies run-to-run (atomics) but the output is order-invariant.
__global__ void compact_kernel(const int* __restrict__ span_ids, const int* __restrict__ masks,
                               const int* __restrict__ flag, const int* __restrict__ pooling,
                               int* __restrict__ cS, int* __restrict__ cE, int* __restrict__ cO,
                               int* __restrict__ cnt) {
    int m = blockIdx.x * 256 + threadIdx.x;
    bool act = flag[0] ? (((const unsigned char*)masks)[m] != 0) : (masks[m] != 0);
    if (act) {
        int idx = atomicAdd(cnt, 1);
        int s = span_ids[2 * m], e = span_ids[2 * m + 1];
        int b = m >> 14;                       // m / NSPAN
        int window = (pooling[0] != 0) ? 1 : 3;
        int cw = min(window, e - s);           // e-s >= 1 always
        int base = (b * 3 + (cw - 1)) * SEQ;
        cS[idx] = base + s;
        cE[idx] = base + (e - cw);
        cO[idx] = m;
    }
}

// ---------------------------------------------------------------------------
// Masked-out rows: out[m] = bias. One wave per row, grid-stride.
__global__ void bias_fill_kernel(const int* __restrict__ masks, const int* __restrict__ flag,
                                 const float* __restrict__ bias, float* __restrict__ out) {
    int wave = (blockIdx.x * 256 + threadIdx.x) >> 6;   // 0..4095
    int lane = threadIdx.x & 63;
    int u8 = flag[0];
    for (int m = wave; m < M_TOT; m += 4096) {
        bool act = u8 ? (((const unsigned char*)masks)[m] != 0) : (masks[m] != 0);
        if (!act) {
            float* o = out + (size_t)m * HID;
#pragma unroll
            for (int c = 0; c < 3; ++c) {
                int h = (lane + c * 64) * 4;
                *(f32x4*)(o + h) = *(const f32x4*)(bias + h);
            }
        }
    }
}

// ---------------------------------------------------------------------------
// M3[b][c][p][h] = max over T[b, p .. p+c] (c = 0,1,2 => window 1,2,3), bf16.
// Rolling-max strip: each block covers 16 positions; token rows read ~1.1x.
// Rows clamped at the sequence end are provably never referenced.
__global__ void prep_m3_kernel(const float* __restrict__ T, bf16* __restrict__ M3) {
    int b = blockIdx.y;
    int p0 = blockIdx.x * 16;
    int t = threadIdx.x;   // 256
    const float* Tb = T + (size_t)b * SEQ * HID;
    bf16* o0 = M3 + (size_t)(b * 3 + 0) * SEQ * HID;
    bf16* o1 = M3 + (size_t)(b * 3 + 1) * SEQ * HID;
    bf16* o2 = M3 + (size_t)(b * 3 + 2) * SEQ * HID;
#pragma unroll
    for (int c = 0; c < 3; ++c) {
        int h = t + c * 256;
        float x0 = Tb[(size_t)p0 * HID + h];
        float x1 = Tb[(size_t)min(p0 + 1, SEQ - 1) * HID + h];
        for (int i = 0; i < 16; ++i) {
            int p = p0 + i;
            float x2 = Tb[(size_t)min(p + 2, SEQ - 1) * HID + h];
            float m2 = fmaxf(x0, x1);
            float m3v = fmaxf(m2, x2);
            size_t off = (size_t)p * HID + h;
            o0[off] = __float2bfloat16(x0);
            o1[off] = __float2bfloat16(m2);
            o2[off] = __float2bfloat16(m3v);
            x0 = x1; x1 = x2;
        }
    }
}

// ---------------------------------------------------------------------------
// Wt[n][k] = bf16(W[k][n]); W is (K2, HID) f32 row-major. 64x64 LDS transpose.
__global__ void prep_wt_kernel(const float* __restrict__ W, bf16* __restrict__ Wt) {
    __shared__ float tile[64][65];
    int k0 = blockIdx.x * 64;
    int n0 = blockIdx.y * 64;
    int t = threadIdx.x;
    int c = t & 63, r4 = t >> 6;
    for (int r = r4; r < 64; r += 4)
        tile[r][c] = W[(size_t)(k0 + r) * HID + n0 + c];
    __syncthreads();
    for (int r = r4; r < 64; r += 4)
        Wt[(size_t)(n0 + r) * K2 + k0 + c] = __float2bfloat16(tile[c][r]);
}

// ---------------------------------------------------------------------------
// GEMM over COMPACTED rows: out[cO[m]][n] = sum_k A[m][k]*W[k][n] + b[n]
// A[m] = [ M3row(cS[m]) | M3row(cE[m]) ]  (gathered via per-lane
// global_load_lds source addresses, never materialized).
// 128x128 tile, 4 waves (2x2 of 64x64), BK=64, mfma_f32_16x16x32_bf16.
// LDS layout: linear [row][128B], 16B-chunk XOR-swizzled (chunk ^= row&7) on
// BOTH the global source and the ds_read side (rule 21: both-or-neither).
__global__ __launch_bounds__(256, 2)
void span_gemm_kernel(const bf16* __restrict__ M3, const bf16* __restrict__ Wt,
                      const int* __restrict__ cS, const int* __restrict__ cE,
                      const int* __restrict__ cO, const int* __restrict__ cnt,
                      const float* __restrict__ bias, float* __restrict__ out) {
    __shared__ char lA[128 * 128];   // 16 KB
    __shared__ char lB[128 * 128];   // 16 KB
    __shared__ int rS[128], rE[128], rO[128];

    const int tid = threadIdx.x;
    const int n0 = blockIdx.x * 128;   // 6 col tiles
    const int m0 = blockIdx.y * 128;   // 512 row tiles (early-exit past count)

    if (m0 >= cnt[0]) return;          // wave-uniform early exit

    if (tid < 128) {
        int m = m0 + tid;
        rS[tid] = cS[m];
        rE[tid] = cE[m];
        rO[tid] = cO[m];
    }
    __syncthreads();

    const int lane = tid & 63, w = tid >> 6;
    const int wr = w >> 1, wc = w & 1;        // wave 2x2 over the 128x128 tile
    const int lr = lane & 15, lg = lane >> 4;

    // Staging geometry: per K-step each operand is 128 rows x 128 B = 8KB
    // = 8 wave-issues of 1KB; 4 issues per thread per operand.
    const int lrow8 = lane >> 3;
    const int chunkp = ((lane & 7) ^ lrow8) << 4;   // swizzled byte offset in row

    const char* aPtr[2][4];
    const char* bPtr[4];
    int ldsOff[4];
#pragma unroll
    for (int it = 0; it < 4; ++it) {
        int i = it * 4 + w;                    // 1KB-issue index 0..31
        int r = i * 8 + lrow8;                 // LDS row 0..127
        aPtr[0][it] = (const char*)M3 + (size_t)rS[r] * (HID * 2) + chunkp;
        aPtr[1][it] = (const char*)M3 + (size_t)rE[r] * (HID * 2) + chunkp;
        bPtr[it]    = (const char*)Wt + (size_t)(n0 + r) * (K2 * 2) + chunkp;
        ldsOff[it]  = i * 1024;                // wave-uniform
    }

    f32x4 acc[4][4];
#pragma unroll
    for (int i = 0; i < 4; i++)
#pragma unroll
        for (int j = 0; j < 4; j++) acc[i][j] = (f32x4){0.f, 0.f, 0.f, 0.f};

    for (int kt = 0; kt < K2; kt += 64) {
        const int half = (kt >= HID) ? 1 : 0;
        const int colB = (kt - (half ? HID : 0)) * 2;   // byte col within M3 row
        const int ktB  = kt * 2;                        // byte col within Wt row
        __syncthreads();   // previous tile fully consumed by all waves
#pragma unroll
        for (int it = 0; it < 4; ++it)
            gll16(aPtr[half][it] + colB, lA + ldsOff[it]);
#pragma unroll
        for (int it = 0; it < 4; ++it)
            gll16(bPtr[it] + ktB, lB + ldsOff[it]);
        __syncthreads();   // vmcnt(0) drained by compiler before barrier
#pragma unroll
        for (int kk = 0; kk < 2; ++kk) {
            const int cb = kk * 4 + lg;        // global 16B-chunk index (k/8)
            s16x8 af[4], bfr[4];
#pragma unroll
            for (int i = 0; i < 4; ++i) {
                int row = wr * 64 + i * 16 + lr;
                af[i] = *(const s16x8*)(lA + row * 128 + ((cb ^ (row & 7)) << 4));
            }
#pragma unroll
            for (int j = 0; j < 4; ++j) {
                int row = wc * 64 + j * 16 + lr;
                bfr[j] = *(const s16x8*)(lB + row * 128 + ((cb ^ (row & 7)) << 4));
            }
#pragma unroll
            for (int i = 0; i < 4; ++i)
#pragma unroll
                for (int j = 0; j < 4; ++j)
                    acc[i][j] = __builtin_amdgcn_mfma_f32_16x16x32_bf16(af[i], bfr[j], acc[i][j], 0, 0, 0);
        }
    }

    // Epilogue: C/D layout (verified m89): col = lane&15, row = (lane>>4)*4 + q
#pragma unroll
    for (int i = 0; i < 4; i++) {
#pragma unroll
        for (int j = 0; j < 4; j++) {
#pragma unroll
            for (int q = 0; q < 4; q++) {
                int mloc = wr * 64 + i * 16 + lg * 4 + q;
                int o = rO[mloc];
                if (o >= 0) {
                    int n = n0 + wc * 64 + j * 16 + lr;
                    out[(size_t)o * HID + n] = acc[i][j][q] + bias[n];
                }
            }
        }
    }
}

// ---------------------------------------------------------------------------
extern "C" void kernel_launch(void* const* d_in, const int* in_sizes, int n_in,
                              void* d_out, int out_size, void* d_ws, size_t ws_size,
                              hipStream_t stream) {
    const float* token_reps = (const float*)d_in[0];
    const int*   span_ids   = (const int*)d_in[1];
    const int*   span_masks = (const int*)d_in[2];
    const int*   pooling    = (const int*)d_in[3];
    const float* W          = (const float*)d_in[4];
    const float* bias       = (const float*)d_in[5];
    float* out = (float*)d_out;

    // ws layout:
    //   [0,4)    mask-mode flag
    //   [4,8)    active count
    //   [64, ..) cS / cE / cO compacted tables (CMP_CAP ints each)
    //   [1MB, +37.75MB) M3   | then Wt (2.25MB)
    char* ws = (char*)d_ws;
    int*  flag = (int*)ws;
    int*  cnt  = (int*)(ws + 4);
    int*  cS   = (int*)(ws + 64);
    int*  cE   = (int*)(ws + 64 + 4 * CMP_CAP);
    int*  cO   = (int*)(ws + 64 + 8 * CMP_CAP);
    bf16* M3   = (bf16*)(ws + (1 << 20));
    const size_t M3_BYTES = (size_t)NB * 3 * SEQ * HID * 2;   // 37,748,736
    bf16* Wt   = (bf16*)(ws + (1 << 20) + M3_BYTES);

    hipMemsetAsync(ws, 0, 64, stream);
    mask_detect_kernel<<<64, 256, 0, stream>>>((const unsigned*)span_masks, flag);
    init_compact_kernel<<<(CMP_CAP + 255) / 256, 256, 0, stream>>>(cS, cE, cO);
    compact_kernel<<<M_TOT / 256, 256, 0, stream>>>(span_ids, span_masks, flag, pooling,
                                                    cS, cE, cO, cnt);
    prep_m3_kernel<<<dim3(SEQ / 16, NB), 256, 0, stream>>>(token_reps, M3);
    prep_wt_kernel<<<dim3(K2 / 64, HID / 64), 256, 0, stream>>>(W, Wt);
    bias_fill_kernel<<<1024, 256, 0, stream>>>(span_masks, flag, bias, out);
    span_gemm_kernel<<<dim3(HID / 128, M_TOT / 128), 256, 0, stream>>>(
        M3, Wt, cS, cE, cO, cnt, bias, out);
}